// Round 1
// baseline (235.335 us; speedup 1.0000x reference)
//
#include <hip/hip_runtime.h>
#include <hip/hip_bf16.h>

#define NANCH 202500
#define PRE_NMS 6000
#define POST_NMS 300
#define KW 94            // ceil(6016/64) words per supp row
#define CAP 8192
#define NBUCK 16384
#define BSHIFT 18
#define IOU_TH 0.7f
#define MIN_SIZE 0.016f
#define TB_PAD 6016      // topbox padded to a multiple of 64
#define RTILE 256        // rank j-tile (small: spread LDS load over many CUs)
#define RITEMS 8         // candidates ranked per thread (register-blocked)
#define SBLK 256         // k_score grid blocks

typedef unsigned long long ull;

// ---------------- shared decode / key helpers ---------------------------
__device__ inline float4 decode_box(const float* __restrict__ loc,
                                    const float* __restrict__ anc, int i) {
    float4 a = ((const float4*)anc)[i];
    float4 t = ((const float4*)loc)[i];
    float pw = a.z - a.x, ph = a.w - a.y;
    float pcx = (a.x + a.z) * 0.5f, pcy = (a.y + a.w) * 0.5f;
    float cx = t.x * pw + pcx, cy = t.y * ph + pcy;
    float w = expf(t.z) * pw, h = expf(t.w) * ph;
    float x1 = fminf(fmaxf(cx - 0.5f * w, 0.f), 1.f);
    float y1 = fminf(fmaxf(cy - 0.5f * h, 0.f), 1.f);
    float x2 = fminf(fmaxf(cx + 0.5f * w, 0.f), 1.f);
    float y2 = fminf(fmaxf(cy + 0.5f * h, 0.f), 1.f);
    return make_float4(x1, y1, x2, y2);
}

__device__ inline unsigned make_key(const float* __restrict__ cls,
                                    const float* __restrict__ loc,
                                    const float* __restrict__ anc, int i) {
    float2 c = ((const float2*)cls)[i];
    float d = c.y - c.x;                       // monotone proxy for softmax[:,1]
    float4 b = decode_box(loc, anc, i);
    bool valid = ((b.z - b.x) >= MIN_SIZE) && ((b.w - b.y) >= MIN_SIZE);
    unsigned ib = __float_as_uint(d);
    unsigned u = (ib & 0x80000000u) ? ~ib : (ib | 0x80000000u);  // monotonic key
    return valid ? u : 0u;                     // invalid -> below everything
}

__device__ inline ull bcast64(ull v, int lane) {
    unsigned lo = (unsigned)v, hi = (unsigned)(v >> 32);
    lo = (unsigned)__shfl((int)lo, lane, 64);
    hi = (unsigned)__shfl((int)hi, lane, 64);
    return ((ull)hi << 32) | lo;
}

// ---------------- K1: keys + per-block LDS histogram ---------------------
// R4 postmortem: global atomic hist had a ~3000-deep hot bucket (d~N(0,1.4)
// crams mass into few float-prefix buckets) -> ~100us of serialized atomics.
// LDS hist absorbs contention; flush adds <=SBLK per bucket, staggered so
// concurrent blocks flush disjoint bucket ranges.
__global__ __launch_bounds__(256) void k_score(const float* __restrict__ cls,
                                               const float* __restrict__ loc,
                                               const float* __restrict__ anc,
                                               unsigned* __restrict__ hist,
                                               unsigned* __restrict__ keyc, int n) {
    __shared__ unsigned lh[NBUCK];             // 64 KB
    int tid = threadIdx.x, bid = blockIdx.x;
    for (int q = tid; q < NBUCK; q += 256) lh[q] = 0u;
    __syncthreads();
    for (int i = bid * 256 + tid; i < n; i += SBLK * 256) {
        unsigned u = make_key(cls, loc, anc, i);
        if (keyc) keyc[i] = u;
        atomicAdd(&lh[u >> BSHIFT], 1u);
    }
    __syncthreads();
    for (int qq = 0; qq < NBUCK / 256; qq++) {
        int q = (qq + bid) & (NBUCK / 256 - 1);     // stagger across blocks
        int b = q * 256 + tid;
        unsigned v = lh[b];
        if (v) atomicAdd(&hist[b], v);
    }
}

// ---------------- K2: find boundary bucket B (rank 6000 from top) -------
__global__ __launch_bounds__(1024) void k_findb(const unsigned* __restrict__ hist,
                                                unsigned* __restrict__ meta) {
    __shared__ unsigned ps[1024];
    int t = threadIdx.x;
    int base = t * (NBUCK / 1024);
    unsigned local = 0;
    for (int b = 0; b < NBUCK / 1024; b++) local += hist[base + b];
    ps[t] = local;
    __syncthreads();
    for (int off = 1; off < 1024; off <<= 1) {
        unsigned add = (t + off < 1024) ? ps[t + off] : 0u;
        __syncthreads();
        ps[t] += add;
        __syncthreads();
    }
    unsigned incl = ps[t];
    unsigned excl = incl - local;
    if (incl >= (unsigned)PRE_NMS && excl < (unsigned)PRE_NMS) {
        unsigned cum = excl;
        int B = base;
        for (int b = NBUCK / 1024 - 1; b >= 0; b--) {
            cum += hist[base + b];
            if (cum >= (unsigned)PRE_NMS) { B = base + b; break; }
        }
        meta[0] = (unsigned)B;
    }
}

// ---------------- K3a: compact (cached keys, wave-aggregated atomic) ----
__global__ __launch_bounds__(256) void k_compactC(const unsigned* __restrict__ keyc,
                                                  unsigned* __restrict__ meta,
                                                  ull* __restrict__ cand, int n) {
    int i = blockIdx.x * blockDim.x + threadIdx.x;
    unsigned u = (i < n) ? keyc[i] : 0u;
    unsigned B = meta[0];
    bool pred = (i < n) && ((u >> BSHIFT) >= B);
    ull mask = __ballot(pred);
    if (!mask) return;
    int lane = threadIdx.x & 63;
    int leader = __builtin_ctzll(mask);
    unsigned base = 0;
    if (lane == leader) base = atomicAdd(&meta[1], (unsigned)__popcll(mask));
    base = (unsigned)__shfl((int)base, leader, 64);
    if (pred) {
        unsigned p = base + (unsigned)__popcll(mask & ((1ull << lane) - 1ull));
        if (p < CAP) cand[p] = ((ull)(~u) << 32) | (unsigned)i;
    }
}

// ---------------- K3b: compact, recompute keys (small-ws fallback) ------
__global__ __launch_bounds__(256) void k_compactR(const float* __restrict__ cls,
                                                  const float* __restrict__ loc,
                                                  const float* __restrict__ anc,
                                                  unsigned* __restrict__ meta,
                                                  ull* __restrict__ cand, int n) {
    int i = blockIdx.x * blockDim.x + threadIdx.x;
    if (i >= n) return;
    unsigned u = make_key(cls, loc, anc, i);
    if ((u >> BSHIFT) >= meta[0]) {
        unsigned p = atomicAdd(&meta[1], 1u);
        if (p < CAP) cand[p] = ((ull)(~u) << 32) | (unsigned)i;
    }
}

// ---------------- K4a: exact rank by counting (register-blocked) --------
// rank[i] = #{j: key_j < key_i}; keys unique -> exact permutation.
// RITEMS candidates/thread: LDS tile broadcast amortized 8x vs R4.
__global__ __launch_bounds__(256) void k_rank(const ull* __restrict__ cand,
                                              const unsigned* __restrict__ meta,
                                              unsigned* __restrict__ rank,
                                              float4* __restrict__ topbox) {
    __shared__ __align__(16) ull tile[RTILE];  // 2 KB
    int tid = threadIdx.x;
    int bx = blockIdx.x, by = blockIdx.y;
    unsigned C = meta[1]; if (C > CAP) C = CAP;
    if (by == 0) {                             // sentinel prefill (before scatter)
        int per = TB_PAD / (CAP / (256 * RITEMS));    // 6016/4 = 1504
        int s0 = bx * per;
        for (int q = tid; q < per; q += 256)
            topbox[s0 + q] = make_float4(-1.f, -1.f, -1.f, -1.f);
    }
    int ibase = bx * 256 * RITEMS;
    ull ki[RITEMS]; unsigned cnt[RITEMS];
    #pragma unroll
    for (int r = 0; r < RITEMS; r++) {
        int i = ibase + r * 256 + tid;
        ki[r] = (i < (int)C) ? cand[i] : ~0ull;
        cnt[r] = 0u;
    }
    int j = by * RTILE + tid;
    tile[tid] = (j < (int)C) ? cand[j] : ~0ull;   // pad = +inf (never < real key)
    __syncthreads();
    const ulonglong2* t2 = (const ulonglong2*)tile;
    for (int q = 0; q < RTILE / 2; q++) {
        ulonglong2 v = t2[q];
        #pragma unroll
        for (int r = 0; r < RITEMS; r++)
            cnt[r] += (unsigned)(v.x < ki[r]) + (unsigned)(v.y < ki[r]);
    }
    #pragma unroll
    for (int r = 0; r < RITEMS; r++)
        if (cnt[r]) atomicAdd(&rank[ibase + r * 256 + tid], cnt[r]);
}

// ---------------- K4b: scatter + decode to rank position ----------------
__global__ __launch_bounds__(256) void k_scatter(const ull* __restrict__ cand,
                                                 const unsigned* __restrict__ meta,
                                                 const unsigned* __restrict__ rank,
                                                 const float* __restrict__ loc,
                                                 const float* __restrict__ anc,
                                                 float4* __restrict__ topbox,
                                                 ull* __restrict__ vmask) {
    int i = blockIdx.x * 256 + threadIdx.x;
    unsigned C = meta[1]; if (C > CAP) C = CAP;
    if (i >= (int)C) return;
    ull kv = cand[i];
    unsigned uu = ~(unsigned)(kv >> 32);
    if (uu == 0u) return;                      // invalid box -> slot stays sentinel
    unsigned r = rank[i];
    if (r >= PRE_NMS) return;                  // outside top-6000
    int idx = (int)(unsigned)kv;
    topbox[r] = decode_box(loc, anc, idx);
    atomicOr(&vmask[r >> 6], 1ull << (r & 63));
}

// ---------------- K5: suppression bitmask --------------------------------
__global__ __launch_bounds__(64) void k_supp(const float4* __restrict__ topbox,
                                             ull* __restrict__ supp) {
    int cb = blockIdx.x, rb = blockIdx.y;
    int i = rb * 64 + threadIdx.x;
    if (cb < rb) {                              // strictly lower triangle
        if (i < PRE_NMS) supp[(size_t)i * KW + cb] = 0ull;
        return;
    }
    __shared__ float4 cbox[64];
    int jt = cb * 64 + threadIdx.x;
    cbox[threadIdx.x] = (jt < PRE_NMS) ? topbox[jt] : make_float4(0.f, 0.f, 0.f, 0.f);
    __syncthreads();
    if (i >= PRE_NMS) return;
    float4 bi = topbox[i];
    float ai = (bi.z - bi.x) * (bi.w - bi.y);
    ull bits = 0ull;
    int j0 = cb * 64;
    for (int jj = 0; jj < 64; jj++) {
        int j = j0 + jj;
        if (j <= i || j >= PRE_NMS) continue;
        float4 bj = cbox[jj];
        float aj = (bj.z - bj.x) * (bj.w - bj.y);
        float lx = fmaxf(bi.x, bj.x), ly = fmaxf(bi.y, bj.y);
        float rx = fminf(bi.z, bj.z), ry = fminf(bi.w, bj.w);
        float iw = fmaxf(rx - lx, 0.f), ih = fmaxf(ry - ly, 0.f);
        float inter = iw * ih;
        float iou = inter / (ai + aj - inter + 1e-12f);
        if (iou > IOU_TH) bits |= (1ull << jj);
    }
    supp[(size_t)i * KW + cb] = bits;
}

// ---------------- K6: serial scan, column-block-wise ---------------------
// R5 postmortem: old scan spent ~560 cy per accepted box (dependent ds_read
// of the LDS diag tile + 2 dependent shfls + LDS klist write). New structure:
// per 64-candidate block, the 64x64 diagonal suppression block lives in
// REGISTERS (lane b holds row c*64+b's word c), so the serial chain per keep
// is ctz -> one shfl-broadcast -> andn (~75 cy). Cross-block suppression is
// a per-lane union (lane = word index: rA0 words 0..63, rA1 words 64..93),
// updated once per block end with 4-deep pipelined independent row loads.
__global__ __launch_bounds__(64) void k_scan(const ull* __restrict__ supp,
                                             const ull* __restrict__ vmask,
                                             const float4* __restrict__ topbox,
                                             float* __restrict__ out) {
    __shared__ int klist[POST_NMS];
    __shared__ ull vm_s[KW];
    int l = threadIdx.x;
    for (int q = l; q < KW; q += 64) vm_s[q] = vmask[q];
    __syncthreads();

    ull rA0 = 0ull, rA1 = 0ull;                // lane l: union word l / word 64+l
    int nk = 0;
    for (int c = 0; c < KW; c++) {
        ull vm = vm_s[c];
        if (!vm) continue;
        ull incoming = (c < 64) ? bcast64(rA0, c) : bcast64(rA1, c - 64);
        ull todo = vm & ~incoming;
        if (!todo) continue;
        int row = c * 64 + l;                  // diag block -> registers
        ull dw = (row < PRE_NMS) ? supp[(size_t)row * KW + c] : 0ull;
        ull keepw = 0ull;
        while (todo) {
            int b = __builtin_ctzll(todo);
            todo &= todo - 1ull;
            keepw |= 1ull << b;
            if (l == 0) klist[nk] = c * 64 + b;
            nk++;
            if (nk == POST_NMS) break;
            todo &= ~bcast64(dw, b);           // the only dependent hop per keep
        }
        if (nk == POST_NMS) break;             // no future blocks -> skip rA fold
        // fold accepted rows into rA: 4 independent row loads per iteration
        ull kw2 = keepw;
        while (kw2) {
            int b0 = __builtin_ctzll(kw2); kw2 &= kw2 - 1ull;
            int b1 = -1, b2 = -1, b3 = -1;
            if (kw2) { b1 = __builtin_ctzll(kw2); kw2 &= kw2 - 1ull; }
            if (kw2) { b2 = __builtin_ctzll(kw2); kw2 &= kw2 - 1ull; }
            if (kw2) { b3 = __builtin_ctzll(kw2); kw2 &= kw2 - 1ull; }
            const ull* r0 = supp + (size_t)(c * 64 + b0) * KW;
            ull a0 = r0[l];
            ull h0 = (l < KW - 64) ? r0[64 + l] : 0ull;
            ull a1 = 0, h1 = 0, a2 = 0, h2 = 0, a3 = 0, h3 = 0;
            if (b1 >= 0) {
                const ull* r = supp + (size_t)(c * 64 + b1) * KW;
                a1 = r[l]; h1 = (l < KW - 64) ? r[64 + l] : 0ull;
            }
            if (b2 >= 0) {
                const ull* r = supp + (size_t)(c * 64 + b2) * KW;
                a2 = r[l]; h2 = (l < KW - 64) ? r[64 + l] : 0ull;
            }
            if (b3 >= 0) {
                const ull* r = supp + (size_t)(c * 64 + b3) * KW;
                a3 = r[l]; h3 = (l < KW - 64) ? r[64 + l] : 0ull;
            }
            rA0 |= a0 | a1 | a2 | a3;
            rA1 |= h0 | h1 | h2 | h3;
        }
    }
    __syncthreads();
    for (int q = l; q < nk; q += 64)
        ((float4*)out)[q] = topbox[klist[q]];
    for (int q = nk + l; q < POST_NMS; q += 64)
        ((float4*)out)[q] = make_float4(0.f, 0.f, 0.f, 0.f);
}

// ---------------- K5s: single-wave streaming NMS (small-ws fallback) ----
__global__ __launch_bounds__(64) void k_nms(const float4* __restrict__ topbox,
                                            float* __restrict__ out) {
    int l = threadIdx.x;
    float4 kb[5];
    int nk = 0;
    for (int q0 = 0; q0 < TB_PAD && nk < POST_NMS; q0 += 64) {
        float4 myb = topbox[q0 + l];
        for (int b = 0; b < 64 && nk < POST_NMS; b++) {
            float4 bb;
            bb.x = __shfl(myb.x, b, 64);
            bb.y = __shfl(myb.y, b, 64);
            bb.z = __shfl(myb.z, b, 64);
            bb.w = __shfl(myb.w, b, 64);
            if (bb.x < 0.f) continue;
            float ab = (bb.z - bb.x) * (bb.w - bb.y);
            bool sup = false;
            #pragma unroll
            for (int r = 0; r < 5; r++) {
                int s = r * 64 + l;
                if (s < nk) {
                    float4 kv = kb[r];
                    float ak = (kv.z - kv.x) * (kv.w - kv.y);
                    float lx = fmaxf(bb.x, kv.x), ly = fmaxf(bb.y, kv.y);
                    float rx = fminf(bb.z, kv.z), ry = fminf(bb.w, kv.w);
                    float iw = fmaxf(rx - lx, 0.f), ih = fmaxf(ry - ly, 0.f);
                    float inter = iw * ih;
                    float iou = inter / (ab + ak - inter + 1e-12f);
                    sup |= (iou > IOU_TH);
                }
            }
            if (!__any(sup)) {
                if (l == (nk & 63)) kb[nk >> 6] = bb;
                if (l < 4) {
                    float v = (l == 0) ? bb.x : (l == 1) ? bb.y : (l == 2) ? bb.z : bb.w;
                    out[4 * nk + l] = v;
                }
                nk++;
            }
        }
    }
    for (int t = nk * 4 + l; t < POST_NMS * 4; t += 64) out[t] = 0.f;
}

extern "C" void kernel_launch(void* const* d_in, const int* in_sizes, int n_in,
                              void* d_out, int out_size, void* d_ws, size_t ws_size,
                              hipStream_t stream) {
    const int N = in_sizes[0] / 2;             // 202500
    const float* cls = (const float*)d_in[0];
    const float* loc = (const float*)d_in[1];
    const float* anc = (const float*)d_in[2];
    float* out = (float*)d_out;

    char* ws = (char*)d_ws;
    size_t off = 0;
    auto take = [&](size_t bytes) {
        size_t o = off;
        off += (bytes + 255) & ~(size_t)255;
        return o;
    };
    // zero-init region: hist + meta/vmask + rank, contiguous -> one memset
    unsigned* hist = (unsigned*)(ws + take((size_t)NBUCK * 4));      // 64 KB
    char*     mblk = ws + take(1024);
    unsigned* meta  = (unsigned*)mblk;
    ull*      vmask = (ull*)(mblk + 256);                            // 94 words
    unsigned* rank = (unsigned*)(ws + take((size_t)CAP * 4));        // 32 KB
    size_t zlen = off;
    // rest
    ull*    cand   = (ull*)(ws + take((size_t)CAP * 8));             // 64 KB
    float4* topbox = (float4*)(ws + take((size_t)TB_PAD * 16));      // 94 KB
    // fast-path extras
    unsigned* keyc = (unsigned*)(ws + take((size_t)N * 4));          // 810 KB
    ull*      supp = (ull*)(ws + take((size_t)PRE_NMS * KW * 8));    // 4.42 MB
    size_t full_need = off;
    const bool fast = (ws_size >= full_need);   // constant across calls -> graph-safe

    hipMemsetAsync(ws, 0, zlen, stream);

    dim3 rgrid(CAP / (256 * RITEMS), CAP / RTILE);   // (4, 32)

    if (fast) {
        k_score<<<SBLK, 256, 0, stream>>>(cls, loc, anc, hist, keyc, N);
        k_findb<<<1, 1024, 0, stream>>>(hist, meta);
        k_compactC<<<(N + 255) / 256, 256, 0, stream>>>(keyc, meta, cand, N);
        k_rank<<<rgrid, 256, 0, stream>>>(cand, meta, rank, topbox);
        k_scatter<<<CAP / 256, 256, 0, stream>>>(cand, meta, rank, loc, anc, topbox, vmask);
        k_supp<<<dim3(KW, KW), 64, 0, stream>>>(topbox, supp);
        k_scan<<<1, 64, 0, stream>>>(supp, vmask, topbox, out);
    } else {
        k_score<<<SBLK, 256, 0, stream>>>(cls, loc, anc, hist, (unsigned*)nullptr, N);
        k_findb<<<1, 1024, 0, stream>>>(hist, meta);
        k_compactR<<<(N + 255) / 256, 256, 0, stream>>>(cls, loc, anc, meta, cand, N);
        k_rank<<<rgrid, 256, 0, stream>>>(cand, meta, rank, topbox);
        k_scatter<<<CAP / 256, 256, 0, stream>>>(cand, meta, rank, loc, anc, topbox, vmask);
        k_nms<<<1, 64, 0, stream>>>(topbox, out);
    }
}

// Round 2
// 209.449 us; speedup vs baseline: 1.1236x; 1.1236x over previous
//
#include <hip/hip_runtime.h>
#include <hip/hip_bf16.h>

#define NANCH 202500
#define PRE_NMS 6000
#define POST_NMS 300
#define KW 94            // ceil(6016/64) words per supp row
#define CAP 8192
#define NBUCK 16384
#define BSHIFT 18
#define IOU_TH 0.7f
#define MIN_SIZE 0.016f
#define TB_PAD 6016      // topbox padded to a multiple of 64
#define RTILE 256        // rank j-tile (small: spread LDS load over many CUs)
#define RITEMS 8         // candidates ranked per thread (register-blocked)
#define SBLK 256         // k_score grid blocks

typedef unsigned long long ull;

// ---------------- shared decode / key helpers ---------------------------
__device__ inline float4 decode_box(const float* __restrict__ loc,
                                    const float* __restrict__ anc, int i) {
    float4 a = ((const float4*)anc)[i];
    float4 t = ((const float4*)loc)[i];
    float pw = a.z - a.x, ph = a.w - a.y;
    float pcx = (a.x + a.z) * 0.5f, pcy = (a.y + a.w) * 0.5f;
    float cx = t.x * pw + pcx, cy = t.y * ph + pcy;
    float w = expf(t.z) * pw, h = expf(t.w) * ph;
    float x1 = fminf(fmaxf(cx - 0.5f * w, 0.f), 1.f);
    float y1 = fminf(fmaxf(cy - 0.5f * h, 0.f), 1.f);
    float x2 = fminf(fmaxf(cx + 0.5f * w, 0.f), 1.f);
    float y2 = fminf(fmaxf(cy + 0.5f * h, 0.f), 1.f);
    return make_float4(x1, y1, x2, y2);
}

__device__ inline unsigned make_key(const float* __restrict__ cls,
                                    const float* __restrict__ loc,
                                    const float* __restrict__ anc, int i) {
    float2 c = ((const float2*)cls)[i];
    float d = c.y - c.x;                       // monotone proxy for softmax[:,1]
    float4 b = decode_box(loc, anc, i);
    bool valid = ((b.z - b.x) >= MIN_SIZE) && ((b.w - b.y) >= MIN_SIZE);
    unsigned ib = __float_as_uint(d);
    unsigned u = (ib & 0x80000000u) ? ~ib : (ib | 0x80000000u);  // monotonic key
    return valid ? u : 0u;                     // invalid -> below everything
}

__device__ inline ull orx64(ull v, int m) {    // OR-butterfly step (2x shfl_xor)
    unsigned lo = (unsigned)v, hi = (unsigned)(v >> 32);
    lo = (unsigned)__shfl_xor((int)lo, m, 64);
    hi = (unsigned)__shfl_xor((int)hi, m, 64);
    return ((ull)hi << 32) | lo;
}

// ---------------- K1: keys + per-block LDS histogram ---------------------
__global__ __launch_bounds__(256) void k_score(const float* __restrict__ cls,
                                               const float* __restrict__ loc,
                                               const float* __restrict__ anc,
                                               unsigned* __restrict__ hist,
                                               unsigned* __restrict__ keyc, int n) {
    __shared__ unsigned lh[NBUCK];             // 64 KB
    int tid = threadIdx.x, bid = blockIdx.x;
    for (int q = tid; q < NBUCK; q += 256) lh[q] = 0u;
    __syncthreads();
    for (int i = bid * 256 + tid; i < n; i += SBLK * 256) {
        unsigned u = make_key(cls, loc, anc, i);
        if (keyc) keyc[i] = u;
        atomicAdd(&lh[u >> BSHIFT], 1u);
    }
    __syncthreads();
    for (int qq = 0; qq < NBUCK / 256; qq++) {
        int q = (qq + bid) & (NBUCK / 256 - 1);     // stagger across blocks
        int b = q * 256 + tid;
        unsigned v = lh[b];
        if (v) atomicAdd(&hist[b], v);
    }
}

// ---------------- K2: find boundary bucket B (rank 6000 from top) -------
__global__ __launch_bounds__(1024) void k_findb(const unsigned* __restrict__ hist,
                                                unsigned* __restrict__ meta) {
    __shared__ unsigned ps[1024];
    int t = threadIdx.x;
    int base = t * (NBUCK / 1024);
    unsigned local = 0;
    for (int b = 0; b < NBUCK / 1024; b++) local += hist[base + b];
    ps[t] = local;
    __syncthreads();
    for (int off = 1; off < 1024; off <<= 1) {
        unsigned add = (t + off < 1024) ? ps[t + off] : 0u;
        __syncthreads();
        ps[t] += add;
        __syncthreads();
    }
    unsigned incl = ps[t];
    unsigned excl = incl - local;
    if (incl >= (unsigned)PRE_NMS && excl < (unsigned)PRE_NMS) {
        unsigned cum = excl;
        int B = base;
        for (int b = NBUCK / 1024 - 1; b >= 0; b--) {
            cum += hist[base + b];
            if (cum >= (unsigned)PRE_NMS) { B = base + b; break; }
        }
        meta[0] = (unsigned)B;
    }
}

// ---------------- K3a: compact (cached keys, wave-aggregated atomic) ----
__global__ __launch_bounds__(256) void k_compactC(const unsigned* __restrict__ keyc,
                                                  unsigned* __restrict__ meta,
                                                  ull* __restrict__ cand, int n) {
    int i = blockIdx.x * blockDim.x + threadIdx.x;
    unsigned u = (i < n) ? keyc[i] : 0u;
    unsigned B = meta[0];
    bool pred = (i < n) && ((u >> BSHIFT) >= B);
    ull mask = __ballot(pred);
    if (!mask) return;
    int lane = threadIdx.x & 63;
    int leader = __builtin_ctzll(mask);
    unsigned base = 0;
    if (lane == leader) base = atomicAdd(&meta[1], (unsigned)__popcll(mask));
    base = (unsigned)__shfl((int)base, leader, 64);
    if (pred) {
        unsigned p = base + (unsigned)__popcll(mask & ((1ull << lane) - 1ull));
        if (p < CAP) cand[p] = ((ull)(~u) << 32) | (unsigned)i;
    }
}

// ---------------- K3b: compact, recompute keys (small-ws fallback) ------
__global__ __launch_bounds__(256) void k_compactR(const float* __restrict__ cls,
                                                  const float* __restrict__ loc,
                                                  const float* __restrict__ anc,
                                                  unsigned* __restrict__ meta,
                                                  ull* __restrict__ cand, int n) {
    int i = blockIdx.x * blockDim.x + threadIdx.x;
    if (i >= n) return;
    unsigned u = make_key(cls, loc, anc, i);
    if ((u >> BSHIFT) >= meta[0]) {
        unsigned p = atomicAdd(&meta[1], 1u);
        if (p < CAP) cand[p] = ((ull)(~u) << 32) | (unsigned)i;
    }
}

// ---------------- K4a: exact rank by counting (register-blocked) --------
__global__ __launch_bounds__(256) void k_rank(const ull* __restrict__ cand,
                                              const unsigned* __restrict__ meta,
                                              unsigned* __restrict__ rank,
                                              float4* __restrict__ topbox) {
    __shared__ __align__(16) ull tile[RTILE];  // 2 KB
    int tid = threadIdx.x;
    int bx = blockIdx.x, by = blockIdx.y;
    unsigned C = meta[1]; if (C > CAP) C = CAP;
    if (by == 0) {                             // sentinel prefill (before scatter)
        int per = TB_PAD / (CAP / (256 * RITEMS));    // 6016/4 = 1504
        int s0 = bx * per;
        for (int q = tid; q < per; q += 256)
            topbox[s0 + q] = make_float4(-1.f, -1.f, -1.f, -1.f);
    }
    int ibase = bx * 256 * RITEMS;
    ull ki[RITEMS]; unsigned cnt[RITEMS];
    #pragma unroll
    for (int r = 0; r < RITEMS; r++) {
        int i = ibase + r * 256 + tid;
        ki[r] = (i < (int)C) ? cand[i] : ~0ull;
        cnt[r] = 0u;
    }
    int j = by * RTILE + tid;
    tile[tid] = (j < (int)C) ? cand[j] : ~0ull;   // pad = +inf (never < real key)
    __syncthreads();
    const ulonglong2* t2 = (const ulonglong2*)tile;
    for (int q = 0; q < RTILE / 2; q++) {
        ulonglong2 v = t2[q];
        #pragma unroll
        for (int r = 0; r < RITEMS; r++)
            cnt[r] += (unsigned)(v.x < ki[r]) + (unsigned)(v.y < ki[r]);
    }
    #pragma unroll
    for (int r = 0; r < RITEMS; r++)
        if (cnt[r]) atomicAdd(&rank[ibase + r * 256 + tid], cnt[r]);
}

// ---------------- K4b: scatter + decode to rank position ----------------
__global__ __launch_bounds__(256) void k_scatter(const ull* __restrict__ cand,
                                                 const unsigned* __restrict__ meta,
                                                 const unsigned* __restrict__ rank,
                                                 const float* __restrict__ loc,
                                                 const float* __restrict__ anc,
                                                 float4* __restrict__ topbox,
                                                 ull* __restrict__ vmask) {
    int i = blockIdx.x * 256 + threadIdx.x;
    unsigned C = meta[1]; if (C > CAP) C = CAP;
    if (i >= (int)C) return;
    ull kv = cand[i];
    unsigned uu = ~(unsigned)(kv >> 32);
    if (uu == 0u) return;                      // invalid box -> slot stays sentinel
    unsigned r = rank[i];
    if (r >= PRE_NMS) return;                  // outside top-6000
    int idx = (int)(unsigned)kv;
    topbox[r] = decode_box(loc, anc, idx);
    atomicOr(&vmask[r >> 6], 1ull << (r & 63));
}

// ---------------- K5: suppression bitmask + transposed diagonal ---------
// Diag blocks (cb==rb) additionally emit tdiag[i]: bit jj set iff in-block
// row jj < i suppresses i. k_scan turns the per-keep dependent hop into a
// register test + __ballot instead of cross-lane bpermute / global loads.
__global__ __launch_bounds__(64) void k_supp(const float4* __restrict__ topbox,
                                             ull* __restrict__ supp,
                                             ull* __restrict__ tdiag) {
    int cb = blockIdx.x, rb = blockIdx.y;
    int i = rb * 64 + threadIdx.x;
    if (cb < rb) {                              // strictly lower triangle
        if (i < PRE_NMS) supp[(size_t)i * KW + cb] = 0ull;
        return;
    }
    __shared__ float4 cbox[64];
    int jt = cb * 64 + threadIdx.x;
    cbox[threadIdx.x] = (jt < PRE_NMS) ? topbox[jt] : make_float4(0.f, 0.f, 0.f, 0.f);
    __syncthreads();
    if (i >= PRE_NMS) return;
    float4 bi = topbox[i];
    float ai = (bi.z - bi.x) * (bi.w - bi.y);
    ull bits = 0ull;
    int j0 = cb * 64;
    if (cb == rb) {
        ull cbits = 0ull;
        for (int jj = 0; jj < 64; jj++) {
            int j = j0 + jj;
            if (j == i || j >= PRE_NMS) continue;
            float4 bj = cbox[jj];
            float aj = (bj.z - bj.x) * (bj.w - bj.y);
            float lx = fmaxf(bi.x, bj.x), ly = fmaxf(bi.y, bj.y);
            float rx = fminf(bi.z, bj.z), ry = fminf(bi.w, bj.w);
            float iw = fmaxf(rx - lx, 0.f), ih = fmaxf(ry - ly, 0.f);
            float inter = iw * ih;
            float iou = inter / (ai + aj - inter + 1e-12f);
            if (iou > IOU_TH) {
                if (j > i) bits |= (1ull << jj);
                else       cbits |= (1ull << jj);
            }
        }
        tdiag[i] = cbits;
    } else {
        for (int jj = 0; jj < 64; jj++) {
            int j = j0 + jj;
            if (j >= PRE_NMS) continue;        // j > i guaranteed (cb > rb)
            float4 bj = cbox[jj];
            float aj = (bj.z - bj.x) * (bj.w - bj.y);
            float lx = fmaxf(bi.x, bj.x), ly = fmaxf(bi.y, bj.y);
            float rx = fminf(bi.z, bj.z), ry = fminf(bi.w, bj.w);
            float iw = fmaxf(rx - lx, 0.f), ih = fmaxf(ry - ly, 0.f);
            float inter = iw * ih;
            float iou = inter / (ai + aj - inter + 1e-12f);
            if (iou > IOU_TH) bits |= (1ull << jj);
        }
    }
    supp[(size_t)i * KW + cb] = bits;
}

// ---------------- K6: serial scan, ballot inner + klist-gather incoming --
// R5 postmortem: both global-latency chains (scattered diag load, rA row
// fold) sat on the serial critical path -> 80us. Now:
//  * per-keep chain = ctz -> (tc>>b)&1 -> __ballot -> andn (pure VALU/SALU,
//    ~40cy); tc comes from tdiag via ONE coalesced load per block.
//  * incoming per block = gather supp[klist[q]*KW+c] over lanes (<=5
//    independent loads, one waitcnt) + 6-step OR butterfly. No running
//    union, no per-keep row loads.
__global__ __launch_bounds__(64) void k_scan(const ull* __restrict__ supp,
                                             const ull* __restrict__ tdiag,
                                             const ull* __restrict__ vmask,
                                             const float4* __restrict__ topbox,
                                             float* __restrict__ out) {
    __shared__ int klist[POST_NMS];
    __shared__ ull vm_s[KW];
    int l = threadIdx.x;
    for (int q = l; q < KW; q += 64) vm_s[q] = vmask[q];
    __syncthreads();
    int nk = 0;
    bool done = false;
    for (int c = 0; c < KW && !done; c++) {
        ull vm = vm_s[c];
        if (!vm) continue;
        ull inc = 0ull;
        if (nk) {                              // union of prior keeps' word c
            for (int q = l; q < nk; q += 64)
                inc |= supp[(size_t)klist[q] * KW + c];
            #pragma unroll
            for (int off = 32; off; off >>= 1)
                inc |= orx64(inc, off);
        }
        ull todo = vm & ~inc;
        if (!todo) continue;
        int row = c * 64 + l;
        ull tc = (row < PRE_NMS) ? tdiag[row] : 0ull;  // coalesced, once/block
        while (todo) {
            int b = __builtin_ctzll(todo);
            todo &= todo - 1ull;
            if (l == 0) klist[nk] = c * 64 + b;
            nk++;
            if (nk == POST_NMS) { done = true; break; }
            ull supb = __ballot(((tc >> b) & 1ull) != 0ull);
            todo &= ~supb;                     // the only dependent hop per keep
        }
    }
    __syncthreads();
    for (int q = l; q < nk; q += 64)
        ((float4*)out)[q] = topbox[klist[q]];
    for (int q = nk + l; q < POST_NMS; q += 64)
        ((float4*)out)[q] = make_float4(0.f, 0.f, 0.f, 0.f);
}

// ---------------- K5s: single-wave streaming NMS (small-ws fallback) ----
__global__ __launch_bounds__(64) void k_nms(const float4* __restrict__ topbox,
                                            float* __restrict__ out) {
    int l = threadIdx.x;
    float4 kb[5];
    int nk = 0;
    for (int q0 = 0; q0 < TB_PAD && nk < POST_NMS; q0 += 64) {
        float4 myb = topbox[q0 + l];
        for (int b = 0; b < 64 && nk < POST_NMS; b++) {
            float4 bb;
            bb.x = __shfl(myb.x, b, 64);
            bb.y = __shfl(myb.y, b, 64);
            bb.z = __shfl(myb.z, b, 64);
            bb.w = __shfl(myb.w, b, 64);
            if (bb.x < 0.f) continue;
            float ab = (bb.z - bb.x) * (bb.w - bb.y);
            bool sup = false;
            #pragma unroll
            for (int r = 0; r < 5; r++) {
                int s = r * 64 + l;
                if (s < nk) {
                    float4 kv = kb[r];
                    float ak = (kv.z - kv.x) * (kv.w - kv.y);
                    float lx = fmaxf(bb.x, kv.x), ly = fmaxf(bb.y, kv.y);
                    float rx = fminf(bb.z, kv.z), ry = fminf(bb.w, kv.w);
                    float iw = fmaxf(rx - lx, 0.f), ih = fmaxf(ry - ly, 0.f);
                    float inter = iw * ih;
                    float iou = inter / (ab + ak - inter + 1e-12f);
                    sup |= (iou > IOU_TH);
                }
            }
            if (!__any(sup)) {
                if (l == (nk & 63)) kb[nk >> 6] = bb;
                if (l < 4) {
                    float v = (l == 0) ? bb.x : (l == 1) ? bb.y : (l == 2) ? bb.z : bb.w;
                    out[4 * nk + l] = v;
                }
                nk++;
            }
        }
    }
    for (int t = nk * 4 + l; t < POST_NMS * 4; t += 64) out[t] = 0.f;
}

extern "C" void kernel_launch(void* const* d_in, const int* in_sizes, int n_in,
                              void* d_out, int out_size, void* d_ws, size_t ws_size,
                              hipStream_t stream) {
    const int N = in_sizes[0] / 2;             // 202500
    const float* cls = (const float*)d_in[0];
    const float* loc = (const float*)d_in[1];
    const float* anc = (const float*)d_in[2];
    float* out = (float*)d_out;

    char* ws = (char*)d_ws;
    size_t off = 0;
    auto take = [&](size_t bytes) {
        size_t o = off;
        off += (bytes + 255) & ~(size_t)255;
        return o;
    };
    // zero-init region: hist + meta/vmask + rank, contiguous -> one memset
    unsigned* hist = (unsigned*)(ws + take((size_t)NBUCK * 4));      // 64 KB
    char*     mblk = ws + take(1024);
    unsigned* meta  = (unsigned*)mblk;
    ull*      vmask = (ull*)(mblk + 256);                            // 94 words
    unsigned* rank = (unsigned*)(ws + take((size_t)CAP * 4));        // 32 KB
    size_t zlen = off;
    // rest
    ull*    cand   = (ull*)(ws + take((size_t)CAP * 8));             // 64 KB
    float4* topbox = (float4*)(ws + take((size_t)TB_PAD * 16));      // 94 KB
    // fast-path extras
    unsigned* keyc = (unsigned*)(ws + take((size_t)N * 4));          // 810 KB
    ull*      supp = (ull*)(ws + take((size_t)PRE_NMS * KW * 8));    // 4.42 MB
    ull*      tdiag = (ull*)(ws + take((size_t)TB_PAD * 8));         // 48 KB
    size_t full_need = off;
    const bool fast = (ws_size >= full_need);   // constant across calls -> graph-safe

    hipMemsetAsync(ws, 0, zlen, stream);

    dim3 rgrid(CAP / (256 * RITEMS), CAP / RTILE);   // (4, 32)

    if (fast) {
        k_score<<<SBLK, 256, 0, stream>>>(cls, loc, anc, hist, keyc, N);
        k_findb<<<1, 1024, 0, stream>>>(hist, meta);
        k_compactC<<<(N + 255) / 256, 256, 0, stream>>>(keyc, meta, cand, N);
        k_rank<<<rgrid, 256, 0, stream>>>(cand, meta, rank, topbox);
        k_scatter<<<CAP / 256, 256, 0, stream>>>(cand, meta, rank, loc, anc, topbox, vmask);
        k_supp<<<dim3(KW, KW), 64, 0, stream>>>(topbox, supp, tdiag);
        k_scan<<<1, 64, 0, stream>>>(supp, tdiag, vmask, topbox, out);
    } else {
        k_score<<<SBLK, 256, 0, stream>>>(cls, loc, anc, hist, (unsigned*)nullptr, N);
        k_findb<<<1, 1024, 0, stream>>>(hist, meta);
        k_compactR<<<(N + 255) / 256, 256, 0, stream>>>(cls, loc, anc, meta, cand, N);
        k_rank<<<rgrid, 256, 0, stream>>>(cand, meta, rank, topbox);
        k_scatter<<<CAP / 256, 256, 0, stream>>>(cand, meta, rank, loc, anc, topbox, vmask);
        k_nms<<<1, 64, 0, stream>>>(topbox, out);
    }
}

// Round 3
// 175.493 us; speedup vs baseline: 1.3410x; 1.1935x over previous
//
#include <hip/hip_runtime.h>
#include <hip/hip_bf16.h>

#define NANCH 202500
#define PRE_NMS 6000
#define POST_NMS 300
#define KW 94            // ceil(6016/64) words per supp row
#define CAP 8192
#define NBUCK 16384
#define BSHIFT 18
#define IOU_TH 0.7f
#define MIN_SIZE 0.016f
#define TB_PAD 6016      // topbox padded to a multiple of 64
#define RTILE 256        // rank j-tile (small: spread LDS load over many CUs)
#define RITEMS 8         // candidates ranked per thread (register-blocked)
#define SBLK 256         // k_score grid blocks

typedef unsigned long long ull;

// ---------------- shared decode / key helpers ---------------------------
__device__ inline float4 decode_box(const float* __restrict__ loc,
                                    const float* __restrict__ anc, int i) {
    float4 a = ((const float4*)anc)[i];
    float4 t = ((const float4*)loc)[i];
    float pw = a.z - a.x, ph = a.w - a.y;
    float pcx = (a.x + a.z) * 0.5f, pcy = (a.y + a.w) * 0.5f;
    float cx = t.x * pw + pcx, cy = t.y * ph + pcy;
    float w = expf(t.z) * pw, h = expf(t.w) * ph;
    float x1 = fminf(fmaxf(cx - 0.5f * w, 0.f), 1.f);
    float y1 = fminf(fmaxf(cy - 0.5f * h, 0.f), 1.f);
    float x2 = fminf(fmaxf(cx + 0.5f * w, 0.f), 1.f);
    float y2 = fminf(fmaxf(cy + 0.5f * h, 0.f), 1.f);
    return make_float4(x1, y1, x2, y2);
}

__device__ inline unsigned make_key(const float* __restrict__ cls,
                                    const float* __restrict__ loc,
                                    const float* __restrict__ anc, int i) {
    float2 c = ((const float2*)cls)[i];
    float d = c.y - c.x;                       // monotone proxy for softmax[:,1]
    float4 b = decode_box(loc, anc, i);
    bool valid = ((b.z - b.x) >= MIN_SIZE) && ((b.w - b.y) >= MIN_SIZE);
    unsigned ib = __float_as_uint(d);
    unsigned u = (ib & 0x80000000u) ? ~ib : (ib | 0x80000000u);  // monotonic key
    return valid ? u : 0u;                     // invalid -> below everything
}

__device__ inline ull orx64(ull v, int m) {    // OR-butterfly step (2x shfl_xor)
    unsigned lo = (unsigned)v, hi = (unsigned)(v >> 32);
    lo = (unsigned)__shfl_xor((int)lo, m, 64);
    hi = (unsigned)__shfl_xor((int)hi, m, 64);
    return ((ull)hi << 32) | lo;
}

// ---------------- K1: keys + per-block LDS histogram ---------------------
__global__ __launch_bounds__(256) void k_score(const float* __restrict__ cls,
                                               const float* __restrict__ loc,
                                               const float* __restrict__ anc,
                                               unsigned* __restrict__ hist,
                                               unsigned* __restrict__ keyc, int n) {
    __shared__ unsigned lh[NBUCK];             // 64 KB
    int tid = threadIdx.x, bid = blockIdx.x;
    for (int q = tid; q < NBUCK; q += 256) lh[q] = 0u;
    __syncthreads();
    for (int i = bid * 256 + tid; i < n; i += SBLK * 256) {
        unsigned u = make_key(cls, loc, anc, i);
        if (keyc) keyc[i] = u;
        atomicAdd(&lh[u >> BSHIFT], 1u);
    }
    __syncthreads();
    for (int qq = 0; qq < NBUCK / 256; qq++) {
        int q = (qq + bid) & (NBUCK / 256 - 1);     // stagger across blocks
        int b = q * 256 + tid;
        unsigned v = lh[b];
        if (v) atomicAdd(&hist[b], v);
    }
}

// ---------------- K2: find boundary bucket B (rank 6000 from top) -------
__global__ __launch_bounds__(1024) void k_findb(const unsigned* __restrict__ hist,
                                                unsigned* __restrict__ meta) {
    __shared__ unsigned ps[1024];
    int t = threadIdx.x;
    int base = t * (NBUCK / 1024);
    unsigned local = 0;
    for (int b = 0; b < NBUCK / 1024; b++) local += hist[base + b];
    ps[t] = local;
    __syncthreads();
    for (int off = 1; off < 1024; off <<= 1) {
        unsigned add = (t + off < 1024) ? ps[t + off] : 0u;
        __syncthreads();
        ps[t] += add;
        __syncthreads();
    }
    unsigned incl = ps[t];
    unsigned excl = incl - local;
    if (incl >= (unsigned)PRE_NMS && excl < (unsigned)PRE_NMS) {
        unsigned cum = excl;
        int B = base;
        for (int b = NBUCK / 1024 - 1; b >= 0; b--) {
            cum += hist[base + b];
            if (cum >= (unsigned)PRE_NMS) { B = base + b; break; }
        }
        meta[0] = (unsigned)B;
    }
}

// ---------------- K3a: compact (cached keys, wave-aggregated atomic) ----
__global__ __launch_bounds__(256) void k_compactC(const unsigned* __restrict__ keyc,
                                                  unsigned* __restrict__ meta,
                                                  ull* __restrict__ cand, int n) {
    int i = blockIdx.x * blockDim.x + threadIdx.x;
    unsigned u = (i < n) ? keyc[i] : 0u;
    unsigned B = meta[0];
    bool pred = (i < n) && ((u >> BSHIFT) >= B);
    ull mask = __ballot(pred);
    if (!mask) return;
    int lane = threadIdx.x & 63;
    int leader = __builtin_ctzll(mask);
    unsigned base = 0;
    if (lane == leader) base = atomicAdd(&meta[1], (unsigned)__popcll(mask));
    base = (unsigned)__shfl((int)base, leader, 64);
    if (pred) {
        unsigned p = base + (unsigned)__popcll(mask & ((1ull << lane) - 1ull));
        if (p < CAP) cand[p] = ((ull)(~u) << 32) | (unsigned)i;
    }
}

// ---------------- K3b: compact, recompute keys (small-ws fallback) ------
__global__ __launch_bounds__(256) void k_compactR(const float* __restrict__ cls,
                                                  const float* __restrict__ loc,
                                                  const float* __restrict__ anc,
                                                  unsigned* __restrict__ meta,
                                                  ull* __restrict__ cand, int n) {
    int i = blockIdx.x * blockDim.x + threadIdx.x;
    if (i >= n) return;
    unsigned u = make_key(cls, loc, anc, i);
    if ((u >> BSHIFT) >= meta[0]) {
        unsigned p = atomicAdd(&meta[1], 1u);
        if (p < CAP) cand[p] = ((ull)(~u) << 32) | (unsigned)i;
    }
}

// ---------------- K4a: exact rank by counting (register-blocked) --------
__global__ __launch_bounds__(256) void k_rank(const ull* __restrict__ cand,
                                              const unsigned* __restrict__ meta,
                                              unsigned* __restrict__ rank,
                                              float4* __restrict__ topbox) {
    __shared__ __align__(16) ull tile[RTILE];  // 2 KB
    int tid = threadIdx.x;
    int bx = blockIdx.x, by = blockIdx.y;
    unsigned C = meta[1]; if (C > CAP) C = CAP;
    if (by == 0) {                             // sentinel prefill (before scatter)
        int per = TB_PAD / (CAP / (256 * RITEMS));    // 6016/4 = 1504
        int s0 = bx * per;
        for (int q = tid; q < per; q += 256)
            topbox[s0 + q] = make_float4(-1.f, -1.f, -1.f, -1.f);
    }
    int ibase = bx * 256 * RITEMS;
    ull ki[RITEMS]; unsigned cnt[RITEMS];
    #pragma unroll
    for (int r = 0; r < RITEMS; r++) {
        int i = ibase + r * 256 + tid;
        ki[r] = (i < (int)C) ? cand[i] : ~0ull;
        cnt[r] = 0u;
    }
    int j = by * RTILE + tid;
    tile[tid] = (j < (int)C) ? cand[j] : ~0ull;   // pad = +inf (never < real key)
    __syncthreads();
    const ulonglong2* t2 = (const ulonglong2*)tile;
    for (int q = 0; q < RTILE / 2; q++) {
        ulonglong2 v = t2[q];
        #pragma unroll
        for (int r = 0; r < RITEMS; r++)
            cnt[r] += (unsigned)(v.x < ki[r]) + (unsigned)(v.y < ki[r]);
    }
    #pragma unroll
    for (int r = 0; r < RITEMS; r++)
        if (cnt[r]) atomicAdd(&rank[ibase + r * 256 + tid], cnt[r]);
}

// ---------------- K4b: scatter + decode to rank position ----------------
__global__ __launch_bounds__(256) void k_scatter(const ull* __restrict__ cand,
                                                 const unsigned* __restrict__ meta,
                                                 const unsigned* __restrict__ rank,
                                                 const float* __restrict__ loc,
                                                 const float* __restrict__ anc,
                                                 float4* __restrict__ topbox,
                                                 ull* __restrict__ vmask) {
    int i = blockIdx.x * 256 + threadIdx.x;
    unsigned C = meta[1]; if (C > CAP) C = CAP;
    if (i >= (int)C) return;
    ull kv = cand[i];
    unsigned uu = ~(unsigned)(kv >> 32);
    if (uu == 0u) return;                      // invalid box -> slot stays sentinel
    unsigned r = rank[i];
    if (r >= PRE_NMS) return;                  // outside top-6000
    int idx = (int)(unsigned)kv;
    topbox[r] = decode_box(loc, anc, idx);
    atomicOr(&vmask[r >> 6], 1ull << (r & 63));
}

// ---------------- K5: suppression bitmask (upper tri only) + dense diag -
// supp[i*KW+cb] bit jj = "i suppresses j=cb*64+jj" (j>i). k_scan's gather
// only reads strictly-upper words (kept rows precede the gathered block),
// so lower-tri blocks write NOTHING now. Diag blocks also write sdg[i]
// (densely stored copy of the diag word) so k_scan can fetch the whole
// 64x64 diag block with ONE coalesced load.
__global__ __launch_bounds__(64) void k_supp(const float4* __restrict__ topbox,
                                             ull* __restrict__ supp,
                                             ull* __restrict__ sdg) {
    int cb = blockIdx.x, rb = blockIdx.y;
    if (cb < rb) return;                        // never read -> skip entirely
    int i = rb * 64 + threadIdx.x;
    __shared__ float4 cbox[64];
    int jt = cb * 64 + threadIdx.x;
    cbox[threadIdx.x] = (jt < PRE_NMS) ? topbox[jt] : make_float4(0.f, 0.f, 0.f, 0.f);
    __syncthreads();
    if (i >= PRE_NMS) return;
    float4 bi = topbox[i];
    float ai = (bi.z - bi.x) * (bi.w - bi.y);
    ull bits = 0ull;
    int j0 = cb * 64;
    for (int jj = 0; jj < 64; jj++) {
        int j = j0 + jj;
        if (j <= i || j >= PRE_NMS) continue;
        float4 bj = cbox[jj];
        float aj = (bj.z - bj.x) * (bj.w - bj.y);
        float lx = fmaxf(bi.x, bj.x), ly = fmaxf(bi.y, bj.y);
        float rx = fminf(bi.z, bj.z), ry = fminf(bi.w, bj.w);
        float iw = fmaxf(rx - lx, 0.f), ih = fmaxf(ry - ly, 0.f);
        float inter = iw * ih;
        float iou = inter / (ai + aj - inter + 1e-12f);
        if (iou > IOU_TH) bits |= (1ull << jj);
    }
    supp[(size_t)i * KW + cb] = bits;
    if (cb == rb) sdg[i] = bits;
}

// ---------------- K6: serial scan, scalar inner loop ---------------------
// R2 postmortem: 430 cy/keep — ballot(VALU+vcc), 64-bit VGPR andn, exec-mask
// dance for the lane-0 klist store, and 2-3 branches per keep, all at full
// dependent latency on one wave. Now the per-keep loop is pure scalar:
//   b = s_ff1(td); m = v_readlane(sd, b) x2; td &= ~(m|bit); keepw |= bit
// (~8 ops, ONE branch). klist append + nk update happen once per block in
// parallel across lanes (prefix popcount of keepw). The 300-cap check moves
// out of the loop: overshoot keeps can't change the first 300 (suppression
// flows forward only), output takes the first 300.
__global__ __launch_bounds__(64) void k_scan(const ull* __restrict__ supp,
                                             const ull* __restrict__ sdg,
                                             const ull* __restrict__ vmask,
                                             const float4* __restrict__ topbox,
                                             float* __restrict__ out) {
    __shared__ int klist[POST_NMS + 64];       // last block may overshoot <64
    __shared__ ull vm_s[KW];
    int l = threadIdx.x;
    for (int q = l; q < KW; q += 64) vm_s[q] = vmask[q];
    __syncthreads();
    int nk = 0;
    for (int c = 0; c < KW && nk < POST_NMS; c++) {
        ull vm = vm_s[c];
        if (!vm) continue;
        int row = c * 64 + l;
        ull sd = (row < PRE_NMS) ? sdg[row] : 0ull;   // coalesced; issued early
        ull inc = 0ull;                        // union of prior keeps' word c
        for (int q = l; q < nk; q += 64)
            inc |= supp[(size_t)klist[q] * KW + c];
        #pragma unroll
        for (int off = 32; off; off >>= 1) inc |= orx64(inc, off);
        ull todo = vm & ~inc;
        unsigned tlo = __builtin_amdgcn_readfirstlane((unsigned)todo);
        unsigned thi = __builtin_amdgcn_readfirstlane((unsigned)(todo >> 32));
        ull td = ((ull)thi << 32) | tlo;       // scalar domain
        if (!td) continue;
        unsigned sdlo = (unsigned)sd, sdhi = (unsigned)(sd >> 32);
        ull keepw = 0ull;
        while (td) {                           // one scalar iteration per keep
            int b = __builtin_ctzll(td);
            unsigned mlo = __builtin_amdgcn_readlane(sdlo, b);
            unsigned mhi = __builtin_amdgcn_readlane(sdhi, b);
            ull m = (((ull)mhi << 32) | mlo) | (1ull << b);
            keepw |= 1ull << b;
            td &= ~m;
        }
        // parallel klist append: bit order == rank order
        int pos = nk + (int)__popcll(keepw & ((1ull << l) - 1ull));
        if ((keepw >> l) & 1ull) klist[pos] = row;
        nk += (int)__popcll(keepw);
        __syncthreads();                       // LDS write->read ordering (uniform path)
    }
    __syncthreads();
    int nout = nk < POST_NMS ? nk : POST_NMS;
    for (int q = l; q < nout; q += 64)
        ((float4*)out)[q] = topbox[klist[q]];
    for (int q = nout + l; q < POST_NMS; q += 64)
        ((float4*)out)[q] = make_float4(0.f, 0.f, 0.f, 0.f);
}

// ---------------- K5s: single-wave streaming NMS (small-ws fallback) ----
__global__ __launch_bounds__(64) void k_nms(const float4* __restrict__ topbox,
                                            float* __restrict__ out) {
    int l = threadIdx.x;
    float4 kb[5];
    int nk = 0;
    for (int q0 = 0; q0 < TB_PAD && nk < POST_NMS; q0 += 64) {
        float4 myb = topbox[q0 + l];
        for (int b = 0; b < 64 && nk < POST_NMS; b++) {
            float4 bb;
            bb.x = __shfl(myb.x, b, 64);
            bb.y = __shfl(myb.y, b, 64);
            bb.z = __shfl(myb.z, b, 64);
            bb.w = __shfl(myb.w, b, 64);
            if (bb.x < 0.f) continue;
            float ab = (bb.z - bb.x) * (bb.w - bb.y);
            bool sup = false;
            #pragma unroll
            for (int r = 0; r < 5; r++) {
                int s = r * 64 + l;
                if (s < nk) {
                    float4 kv = kb[r];
                    float ak = (kv.z - kv.x) * (kv.w - kv.y);
                    float lx = fmaxf(bb.x, kv.x), ly = fmaxf(bb.y, kv.y);
                    float rx = fminf(bb.z, kv.z), ry = fminf(bb.w, kv.w);
                    float iw = fmaxf(rx - lx, 0.f), ih = fmaxf(ry - ly, 0.f);
                    float inter = iw * ih;
                    float iou = inter / (ab + ak - inter + 1e-12f);
                    sup |= (iou > IOU_TH);
                }
            }
            if (!__any(sup)) {
                if (l == (nk & 63)) kb[nk >> 6] = bb;
                if (l < 4) {
                    float v = (l == 0) ? bb.x : (l == 1) ? bb.y : (l == 2) ? bb.z : bb.w;
                    out[4 * nk + l] = v;
                }
                nk++;
            }
        }
    }
    for (int t = nk * 4 + l; t < POST_NMS * 4; t += 64) out[t] = 0.f;
}

extern "C" void kernel_launch(void* const* d_in, const int* in_sizes, int n_in,
                              void* d_out, int out_size, void* d_ws, size_t ws_size,
                              hipStream_t stream) {
    const int N = in_sizes[0] / 2;             // 202500
    const float* cls = (const float*)d_in[0];
    const float* loc = (const float*)d_in[1];
    const float* anc = (const float*)d_in[2];
    float* out = (float*)d_out;

    char* ws = (char*)d_ws;
    size_t off = 0;
    auto take = [&](size_t bytes) {
        size_t o = off;
        off += (bytes + 255) & ~(size_t)255;
        return o;
    };
    // zero-init region: hist + meta/vmask + rank, contiguous -> one memset
    unsigned* hist = (unsigned*)(ws + take((size_t)NBUCK * 4));      // 64 KB
    char*     mblk = ws + take(1024);
    unsigned* meta  = (unsigned*)mblk;
    ull*      vmask = (ull*)(mblk + 256);                            // 94 words
    unsigned* rank = (unsigned*)(ws + take((size_t)CAP * 4));        // 32 KB
    size_t zlen = off;
    // rest
    ull*    cand   = (ull*)(ws + take((size_t)CAP * 8));             // 64 KB
    float4* topbox = (float4*)(ws + take((size_t)TB_PAD * 16));      // 94 KB
    // fast-path extras
    unsigned* keyc = (unsigned*)(ws + take((size_t)N * 4));          // 810 KB
    ull*      supp = (ull*)(ws + take((size_t)PRE_NMS * KW * 8));    // 4.42 MB
    ull*      sdg  = (ull*)(ws + take((size_t)TB_PAD * 8));          // 48 KB
    size_t full_need = off;
    const bool fast = (ws_size >= full_need);   // constant across calls -> graph-safe

    hipMemsetAsync(ws, 0, zlen, stream);

    dim3 rgrid(CAP / (256 * RITEMS), CAP / RTILE);   // (4, 32)

    if (fast) {
        k_score<<<SBLK, 256, 0, stream>>>(cls, loc, anc, hist, keyc, N);
        k_findb<<<1, 1024, 0, stream>>>(hist, meta);
        k_compactC<<<(N + 255) / 256, 256, 0, stream>>>(keyc, meta, cand, N);
        k_rank<<<rgrid, 256, 0, stream>>>(cand, meta, rank, topbox);
        k_scatter<<<CAP / 256, 256, 0, stream>>>(cand, meta, rank, loc, anc, topbox, vmask);
        k_supp<<<dim3(KW, KW), 64, 0, stream>>>(topbox, supp, sdg);
        k_scan<<<1, 64, 0, stream>>>(supp, sdg, vmask, topbox, out);
    } else {
        k_score<<<SBLK, 256, 0, stream>>>(cls, loc, anc, hist, (unsigned*)nullptr, N);
        k_findb<<<1, 1024, 0, stream>>>(hist, meta);
        k_compactR<<<(N + 255) / 256, 256, 0, stream>>>(cls, loc, anc, meta, cand, N);
        k_rank<<<rgrid, 256, 0, stream>>>(cand, meta, rank, topbox);
        k_scatter<<<CAP / 256, 256, 0, stream>>>(cand, meta, rank, loc, anc, topbox, vmask);
        k_nms<<<1, 64, 0, stream>>>(topbox, out);
    }
}